// Round 1
// baseline (26872.397 us; speedup 1.0000x reference)
//
#include <hip/hip_runtime.h>
#include <stdint.h>

// LSTM persistent-pair kernel for MI355X.
// Design: batch-split across 128 WG-pairs (256 WGs x 512 thr). Each WG holds
// the fp16-packed weights for ONE hidden half (4 gates x 128 j x 384 K) in
// 192 VGPRs/thread. Per step: dot2 gate GEMV from LDS hx = [x_t | h], gate
// nonlinearities by 128 threads, pairwise h-half exchange via agent-scope
// atomics in d_ws (2-slot ring + monotone flag), fused out-projection.
// No grid sync, no big workspace (132 KB of d_ws).

#define T_SEQ 2048
#define BATCH 128
#define IN_D  128
#define HID   256
#define OUTD  64

typedef _Float16 half2_t __attribute__((ext_vector_type(2)));

__device__ __forceinline__ float dot2f(uint32_t w, uint32_t h, float acc) {
#if __has_builtin(__builtin_amdgcn_fdot2)
  return __builtin_amdgcn_fdot2(__builtin_bit_cast(half2_t, w),
                                __builtin_bit_cast(half2_t, h), acc, false);
#else
  half2_t a = __builtin_bit_cast(half2_t, w);
  half2_t b = __builtin_bit_cast(half2_t, h);
  return acc + (float)a[0] * (float)b[0] + (float)a[1] * (float)b[1];
#endif
}

__device__ __forceinline__ uint32_t pack2(float a, float b) {
  union { _Float16 h[2]; uint32_t u; } u_;
  u_.h[0] = (_Float16)a;
  u_.h[1] = (_Float16)b;
  return u_.u;
}

__device__ __forceinline__ float sigm(float v) { return 1.f / (1.f + __expf(-v)); }
__device__ __forceinline__ float tanhx(float v) {
  float a = fabsf(v);
  float e = __expf(2.f * a);
  float r = 1.f - 2.f / (e + 1.f);
  return v < 0.f ? -r : r;
}

__global__ __launch_bounds__(512, 2)
void lstm_persist(const float* __restrict__ x,   const float* __restrict__ Wih,
                  const float* __restrict__ Whh, const float* __restrict__ bih,
                  const float* __restrict__ bhh, const float* __restrict__ Wout,
                  const float* __restrict__ bout_g, float* __restrict__ out,
                  uint32_t* flags, uint32_t* exch)
{
  // hx halves: [0:128) = x_t (fp16), [128:384) = h (fp16); stored as dwords (pairs)
  __shared__ alignas(16) uint32_t hx[192];
  __shared__ alignas(16) float pg[128 * 16];  // gate partials [jj][q][ks]
  __shared__ alignas(16) float po[32 * 16];   // outproj partials [oo][os]
  __shared__ alignas(16) float bs4[128 * 4];  // b_ih+b_hh for local rows [jj][q]

  const int tid = threadIdx.x;
  const int w   = blockIdx.x;
  const int p   = w & 127;    // batch row
  const int s   = w >> 7;     // hidden half (0: j 0..127, 1: j 128..255)
  const int pw  = w ^ 128;    // partner WG (same XCD under %8 round-robin)
  const int jj  = tid >> 2, ks = tid & 3;   // gate-dot layout: 128 j x 4 K-slices
  const int oo  = tid >> 4, os = tid & 15;  // outproj layout:  32 o x 16 K-slices

  // ---- load fused [W_ih | W_hh] rows for this half into registers (fp16 pairs)
  // thread owns rows {q*256 + s*128 + jj : q=0..3}, K-cols [ks*96, ks*96+96)
  uint32_t wreg[192];
  #pragma unroll
  for (int q = 0; q < 4; ++q) {
    const int row = q * 256 + (s << 7) + jj;
    const float* ih = Wih + (size_t)row * IN_D;
    const float* hh = Whh + (size_t)row * HID - IN_D;  // so (hh + k) == Whh[row][k-128]
    #pragma unroll
    for (int i4 = 0; i4 < 24; ++i4) {
      const int k = ks * 96 + i4 * 4;
      const float4 v = *(const float4*)((k < IN_D ? ih : hh) + k);
      wreg[q * 48 + i4 * 2    ] = pack2(v.x, v.y);
      wreg[q * 48 + i4 * 2 + 1] = pack2(v.z, v.w);
    }
  }
  // ---- out-projection weights: thread owns W_out[s*32+oo][os*16 .. +16)
  uint32_t wout[8];
  {
    const int o = (s << 5) + oo;
    const float* wo = Wout + (size_t)o * HID + os * 16;
    #pragma unroll
    for (int i4 = 0; i4 < 4; ++i4) {
      const float4 v = *(const float4*)(wo + i4 * 4);
      wout[i4 * 2    ] = pack2(v.x, v.y);
      wout[i4 * 2 + 1] = pack2(v.z, v.w);
    }
  }
  // ---- biases
  {
    const int q = tid & 3, j2 = tid >> 2;
    const int row = q * 256 + (s << 7) + j2;
    bs4[j2 * 4 + q] = bih[row] + bhh[row];
  }
  float bo = 0.f;
  if (tid >= 256 && tid < 288) bo = bout_g[(s << 5) + (tid - 256)];

  // ---- init: h = 0, x-part = x[0][p][:]
  if (tid >= 64 && tid < 192) hx[tid] = 0u;
  if (tid >= 128 && tid < 256) {
    const float xv = x[(size_t)p * IN_D + (tid - 128)];
    ((_Float16*)hx)[tid - 128] = (_Float16)xv;
  }
  float c = 0.f;
  __syncthreads();

  // loop invariant entering step t: hx = [x_t | h(t-1)]
  for (int t = 0; t <= T_SEQ; ++t) {
    // ---------------- phase 1: dot products ----------------
    float xnext = 0.f;
    if (t < T_SEQ) {
      if (tid >= 128 && tid < 256 && (t + 1) < T_SEQ)
        xnext = x[(size_t)(t + 1) * BATCH * IN_D + (size_t)p * IN_D + (tid - 128)];
      float acc[4] = {0.f, 0.f, 0.f, 0.f};
      const uint4* hp = (const uint4*)(hx + ks * 48);
      #pragma unroll
      for (int ci = 0; ci < 12; ++ci) {
        const uint4 hv = hp[ci];
        #pragma unroll
        for (int q = 0; q < 4; ++q) {
          const int b0 = q * 48 + ci * 4;
          acc[q] = dot2f(wreg[b0    ], hv.x, acc[q]);
          acc[q] = dot2f(wreg[b0 + 1], hv.y, acc[q]);
          acc[q] = dot2f(wreg[b0 + 2], hv.z, acc[q]);
          acc[q] = dot2f(wreg[b0 + 3], hv.w, acc[q]);
        }
      }
      #pragma unroll
      for (int q = 0; q < 4; ++q) pg[(jj << 4) + (q << 2) + ks] = acc[q];
    }
    if (t >= 1) {  // out-projection for step t-1 uses h(t-1) currently in hx
      const uint4* hq = (const uint4*)(hx + 64) + (os << 1);
      const uint4 h0 = hq[0], h1 = hq[1];
      float oa = 0.f;
      oa = dot2f(wout[0], h0.x, oa);
      oa = dot2f(wout[1], h0.y, oa);
      oa = dot2f(wout[2], h0.z, oa);
      oa = dot2f(wout[3], h0.w, oa);
      oa = dot2f(wout[4], h1.x, oa);
      oa = dot2f(wout[5], h1.y, oa);
      oa = dot2f(wout[6], h1.z, oa);
      oa = dot2f(wout[7], h1.w, oa);
      po[(oo << 4) + os] = oa;
    }
    __syncthreads();
    // ---------------- phase 2: reduce + cell update / out store ----------------
    if (t < T_SEQ && tid < 128) {
      const float4* pgf = (const float4*)pg + (tid << 2);
      const float4 P0 = pgf[0], P1 = pgf[1], P2 = pgf[2], P3 = pgf[3];
      const float4 bv = ((const float4*)bs4)[tid];
      const float gi = bv.x + ((P0.x + P0.y) + (P0.z + P0.w));
      const float gf = bv.y + ((P1.x + P1.y) + (P1.z + P1.w));
      const float gg = bv.z + ((P2.x + P2.y) + (P2.z + P2.w));
      const float go = bv.w + ((P3.x + P3.y) + (P3.z + P3.w));
      const float iv = sigm(gi), fv = sigm(gf), gv = tanhx(gg), ov = sigm(go);
      c = fv * c + iv * gv;
      const float hn = ov * tanhx(c);
      ((_Float16*)hx)[128 + (s << 7) + tid] = (_Float16)hn;
    } else if (t >= 1 && tid >= 256 && tid < 288) {
      const int o2 = tid - 256;
      const float4* pof = (const float4*)po + (o2 << 2);
      const float4 q0 = pof[0], q1 = pof[1], q2 = pof[2], q3 = pof[3];
      const float v = bo
          + (((q0.x + q0.y) + (q0.z + q0.w)) + ((q1.x + q1.y) + (q1.z + q1.w)))
          + (((q2.x + q2.y) + (q2.z + q2.w)) + ((q3.x + q3.y) + (q3.z + q3.w)));
      out[((size_t)(t - 1) * BATCH + p) * OUTD + (s << 5) + o2] = v;
    }
    __syncthreads();
    // ---------------- phase 3: pairwise h-half exchange ----------------
    if (t < T_SEQ) {
      if (tid < 64) {
        // publish local h half (64 dwords) then release flag (wave-uniform order)
        const uint32_t v = hx[64 + (s << 6) + tid];
        __hip_atomic_store(exch + ((((size_t)w << 1) | (t & 1)) << 6) + tid, v,
                           __ATOMIC_RELAXED, __HIP_MEMORY_SCOPE_AGENT);
        __threadfence();
        if (tid == 0)
          __hip_atomic_store(flags + w, (uint32_t)(t + 1),
                             __ATOMIC_RELEASE, __HIP_MEMORY_SCOPE_AGENT);
      } else if (tid < 128) {
        const int l = tid - 64;
        const uint32_t want = (uint32_t)(t + 1);
        while (__hip_atomic_load(flags + pw, __ATOMIC_RELAXED,
                                 __HIP_MEMORY_SCOPE_AGENT) < want) {}
        __threadfence();
        const uint32_t v = __hip_atomic_load(
            exch + ((((size_t)pw << 1) | (t & 1)) << 6) + l,
            __ATOMIC_RELAXED, __HIP_MEMORY_SCOPE_AGENT);
        hx[64 + ((s ^ 1) << 6) + l] = v;
      } else if (tid < 256) {
        if ((t + 1) < T_SEQ)
          ((_Float16*)hx)[tid - 128] = (_Float16)xnext;
      }
    }
    __syncthreads();
  }
}

extern "C" void kernel_launch(void* const* d_in, const int* in_sizes, int n_in,
                              void* d_out, int out_size, void* d_ws, size_t ws_size,
                              hipStream_t stream) {
  (void)in_sizes; (void)n_in; (void)out_size; (void)ws_size;
  const float* x    = (const float*)d_in[0];
  const float* Wih  = (const float*)d_in[1];
  const float* Whh  = (const float*)d_in[2];
  const float* bih  = (const float*)d_in[3];
  const float* bhh  = (const float*)d_in[4];
  const float* Wout = (const float*)d_in[5];
  const float* bout = (const float*)d_in[6];
  float* out = (float*)d_out;

  uint32_t* flags = (uint32_t*)d_ws;                   // 256 dwords
  uint32_t* exch  = (uint32_t*)((char*)d_ws + 1024);   // 256 WG x 2 ring x 64 dwords

  // d_ws is re-poisoned to 0xAA before every launch; flags MUST start at 0.
  hipMemsetAsync(d_ws, 0, 1024, stream);
  hipLaunchKernelGGL(lstm_persist, dim3(256), dim3(512), 0, stream,
                     x, Wih, Whh, bih, bhh, Wout, bout, out, flags, exch);
}